// Round 8
// baseline (509.450 us; speedup 1.0000x reference)
//
#include <hip/hip_runtime.h>
#include <climits>

// CTC-like forward scan. R8: skewed single-wave pipeline.
// Lane l owns positions 8l+1..8l+8 and runs l steps behind lane l-1
// (skew=1). Boundary value (left neighbor's F[7]) travels via one
// ds_bpermute per step with 2 steps of pipeline slack. All exponent-frame
// bookkeeping (renorm, down-only squash, neighbor scale factors) happens
// once per 8-step window; within the window the incoming-frame schedule is
// deterministic: steps u=0,1 consume pre-renorm producer values (sA0),
// u>=2 post-renorm (sA1).
// LDS ring: 1536 rows x 40B (10-word stride -> ~2-way bank conflicts) plus
// an 8-row replica so in-window row advance never needs a wrap check.
// Staging: 2 global dwordx4 -> 4 ds_write_b64 per 64-row chunk, 2 chunks
// ahead. Gathers are consumed BEFORE new prefetches are issued each step,
// keeping the DS queue <= 11 (inside the 4-bit lgkmcnt range; R7 exceeded
// it and paid a forced-drain stall every step).

#define TT 4096
#define BB 64
#define PP 512
#define LN2F 0.69314718055994531f

#define RROWS 1536
#define RINGW (RROWS * 10)          // 15360 words
#define REPW  80                    // 8-row replica
#define GARRW (RINGW + REPW)        // garr base word = 15440

// ---- prepass: x[t][b][5] -> xT[b][t][8] (32B rows), exp'd, coalesced ----
__global__ __launch_bounds__(256, 1)
void ctc_prepass(const float* __restrict__ x, float* __restrict__ xT) {
    __shared__ float stage[32 * 320];              // 40960 B
    const int t0 = blockIdx.x * 32;
    const float4* g4 = (const float4*)(x + (size_t)t0 * 320);
    float4* s4 = (float4*)stage;
    for (int i = threadIdx.x; i < 2560; i += 256) s4[i] = g4[i];
    __syncthreads();
    const int j = threadIdx.x, tr = j >> 3, w = j & 7;
    for (int b = 0; b < 64; ++b) {
        float v = (w < 5) ? __expf(stage[tr * 320 + b * 5 + w]) : 0.0f;
        xT[((size_t)b * TT + t0 + tr) * 8 + w] = v;
    }
}

__global__ __launch_bounds__(64, 1)
void ctc_scan(const float* __restrict__ xT, const int* __restrict__ seqs,
              const int* __restrict__ seqlens, float* __restrict__ out) {
    __shared__ float lds[GARRW + 513];             // 63812 B total

    const int b = blockIdx.x;
    const int l = threadIdx.x;                     // 0..63
    const bool lane0 = (l == 0);
    const int permA = 4 * (l - 1);                 // bpermute source = lane l-1

    int vw[9];
#pragma unroll
    for (int i = 0; i < 8; ++i) vw[i] = seqs[b * PP + 8 * l + i];
    vw[8] = 4;                                     // stay word

    const float* gsrc = xT + ((size_t)b * TT) * 8; // packed 32B rows

    // ---- staging helpers (chunk = 64 rows; LDS slot = 640 words) ----
    auto stageLoad = [&](int c, float4& A, float4& B) {
        const float4* p = (const float4*)(gsrc + (size_t)c * 512);
        A = p[l]; B = p[64 + l];
    };
    auto stageWrite = [&](int slot, const float4& A, const float4& B) {
        const int base = slot * 640;
        const int r0 = (l >> 1), h4 = 4 * (l & 1);
        const int d0 = base + 10 * r0 + h4;            // rows 0..31 of chunk
        const int d1 = base + 10 * (32 + r0) + h4;     // rows 32..63
        *(float2*)&lds[d0]     = make_float2(A.x, A.y);
        *(float2*)&lds[d0 + 2] = make_float2(A.z, A.w);
        *(float2*)&lds[d1]     = make_float2(B.x, B.y);
        *(float2*)&lds[d1 + 2] = make_float2(B.z, B.w);
        if (slot == 0 && l < 16) {                     // replica rows 0..7
            const int dr = RINGW + 10 * r0 + h4;
            *(float2*)&lds[dr]     = make_float2(A.x, A.y);
            *(float2*)&lds[dr + 2] = make_float2(A.z, A.w);
        }
    };

    // ---- state ----
    float F[8], Fs[8];
#pragma unroll
    for (int i = 0; i < 8; ++i) { F[i] = 0.0f; Fs[i] = 0.0f; }
    float F0 = lane0 ? 1.0f : 0.0f, F0s = 0.0f;
    int M = 0, M0 = 0, Ms = 0, M0s = 0, Mp = 0;
    float fl0 = 0.0f, fl1 = 0.0f;                  // boundary pipe (slot u&1)
    float sA0 = 1.0f, sA1 = 1.0f, sF0 = 1.0f;

    // ---- prologue: stage chunks 0,1; preload chunk 2 ----
    float4 A0, B0, A1, B1, Ap, Bp;
    stageLoad(0, A0, B0); stageLoad(1, A1, B1);
    stageWrite(0, A0, B0); stageWrite(1, A1, B1);
    stageLoad(2, Ap, Bp);
    __syncthreads();

    // gather addresses: row (0 - l) mod 1536, word units
    int rb = ((1536 - l) % 1536) * 10;             // l==0 -> row 0
    int Aw[9];
#pragma unroll
    for (int i = 0; i < 9; ++i) Aw[i] = rb + vw[i];

    float gbuf[4][9];
#pragma unroll
    for (int i = 0; i < 9; ++i) {                  // rows (0-l), (1-l)
        gbuf[0][i] = lds[Aw[i]];
        gbuf[1][i] = lds[Aw[i] + 10];
    }
    rb += 20;                                       // advance to prefetch row (2-l)
    {
        const bool wr = rb >= RINGW;
        const int sub = wr ? RINGW : 0;
        rb -= sub;
#pragma unroll
        for (int i = 0; i < 9; ++i) Aw[i] += 20 - sub;
    }

    int slot = 2;                                   // LDS slot just written... next is 2
    for (int c = 0; c < 65; ++c) {
        // stage chunk c+2 (regs loaded last iteration), load chunk c+3
        stageWrite(slot, Ap, Bp);
        slot = (slot + 1 == 24) ? 0 : slot + 1;
        { int cn = (c + 3 > 63) ? 63 : (c + 3); stageLoad(cn, Ap, Bp); }

        const int gbase_c = c * 64;
        for (int w8 = 0; w8 < 8; ++w8) {
            // ---- window bookkeeping (once per 8 steps) ----
            float m = F[0];
#pragma unroll
            for (int i = 1; i < 8; ++i) m = fmaxf(m, F[i]);
            int e2 = ((__float_as_int(m) >> 23) & 0xFF) - 127;
            e2 = (m > 0.0f) ? e2 : 0;
#pragma unroll
            for (int i = 0; i < 8; ++i) F[i] = ldexpf(F[i], -e2);
            M += e2;
            int e0 = ((__float_as_int(F0) >> 23) & 0xFF) - 127;
            e0 = (F0 > 0.0f) ? e0 : 0;
            F0 = ldexpf(F0, -e0);
            M0 += e0;

            const int Mn = __builtin_amdgcn_ds_bpermute(permA, M);
            const int NEGB = INT_MIN / 4;
            const int Mpe = lane0 ? NEGB : Mp;      // producer old frame
            const int Mne = lane0 ? NEGB : Mn;      // producer new frame
            const int d00 = lane0 ? (M0 - M) : NEGB;
            int d0 = Mpe - M, d1 = Mne - M;
            int dmax = d0 > d1 ? d0 : d1;
            dmax = dmax > d00 ? dmax : d00;
            dmax = dmax > 0 ? dmax : 0;
#pragma unroll
            for (int i = 0; i < 8; ++i) F[i] = ldexpf(F[i], -dmax);
            M += dmax;
            d0 -= dmax; d1 -= dmax;
            sA0 = ldexpf(1.0f, d0);
            sA1 = ldexpf(1.0f, d1);
            int dF0 = M0 - M; dF0 = dF0 > 0 ? 0 : dF0;
            sF0 = ldexpf(1.0f, dF0);
            Mp = Mn;

            const int gbase = gbase_c + w8 * 8;     // global step of u=0

            // ---- 8 steps: consume first, prefetch after (lgkm queue <= 11) ----
#pragma unroll
            for (int u = 0; u < 8; ++u) {
                const float S = gbuf[u & 3][8];
                const float sAu = (u < 2) ? sA0 : sA1;
                const float flv = (u & 1) ? fl1 : fl0;
                float fin = flv * sAu;
                fin = lane0 ? F0 * sF0 : fin;

                F[7] = fmaf(F[7], S, F[6] * gbuf[u & 3][7]);
                const int bp = __builtin_amdgcn_ds_bpermute(permA, __float_as_int(F[7]));
#pragma unroll
                for (int i = 6; i >= 1; --i)
                    F[i] = fmaf(F[i], S, F[i - 1] * gbuf[u & 3][i]);
                F[0] = fmaf(F[0], S, fin * gbuf[u & 3][0]);
                F0 *= S;

                // prefetch row (gbase+u+2-l) into slot (u+2)&3
#pragma unroll
                for (int i = 0; i < 9; ++i)
                    gbuf[(u + 2) & 3][i] = lds[Aw[i] + 10 * u];

                if ((u & 1)) fl1 = __int_as_float(bp); else fl0 = __int_as_float(bp);

                if (gbase + u - l == TT - 1) {      // snapshot final state
#pragma unroll
                    for (int i = 0; i < 8; ++i) Fs[i] = F[i];
                    Ms = M; F0s = F0; M0s = M0;
                }
            }

            // advance gather addresses by 8 rows, wrap at ring end
            rb += 80;
            const bool wr = rb >= RINGW;
            const int sub = wr ? RINGW : 0;
            rb -= sub;
            const int adv = 80 - sub;
#pragma unroll
            for (int i = 0; i < 9; ++i) Aw[i] += adv;
        }
    }

    // ---- epilogue: log2 reconstruction (denormal-safe) ----
#pragma unroll
    for (int i = 0; i < 8; ++i) {
        float v = fmaxf(Fs[i] * 16777216.0f, 1e-38f);
        lds[GARRW + 8 * l + 1 + i] = __log2f(v) - 24.0f + (float)Ms;
    }
    if (lane0) {
        float v0 = fmaxf(F0s * 16777216.0f, 1e-38f);
        lds[GARRW + 0] = __log2f(v0) - 24.0f + (float)M0s;
    }
    __syncthreads();
    if (lane0) {
        const int sl = seqlens[b];
        out[b] = -(lds[GARRW + sl] * LN2F) / (float)TT;
    }
}

extern "C" void kernel_launch(void* const* d_in, const int* in_sizes, int n_in,
                              void* d_out, int out_size, void* d_ws, size_t ws_size,
                              hipStream_t stream) {
    const float* x       = (const float*)d_in[0];
    const int*   seqs    = (const int*)d_in[1];
    const int*   seqlens = (const int*)d_in[2];
    float*       out     = (float*)d_out;
    float*       xT      = (float*)d_ws;           // BB*TT*8 floats = 8.39 MB

    ctc_prepass<<<TT / 32, 256, 0, stream>>>(x, xT);
    ctc_scan<<<BB, 64, 0, stream>>>(xT, seqs, seqlens, out);
}

// Round 9
// 454.771 us; speedup vs baseline: 1.1202x; 1.1202x over previous
//
#include <hip/hip_runtime.h>

// CTC-like forward scan. R9: single wave per batch element, DS-minimal step.
// R7/R8 post-mortem: both plateaued at ~445us because ~10 DS ops/step
// (gathers + bpermute) overflow the 4-bit lgkmcnt precise-wait range ->
// per-step latency drains. R9 cuts the step to ONE ds_read_b128 (16B packed
// row, broadcast to all lanes, prefetched 2 steps ahead) and moves ALL
// cross-lane traffic to VALU (update_dpp row_shr:1 + readlane patches).
// V-values are bf16 (packed pairs selected by v_perm_b32 with per-lane
// precomputed byte controls); S stays f32. Exponent-frame machinery
// (per-lane M, down-only alignment, renorm every 8 steps) verbatim from the
// R7 kernel that passed with absmax 0.0.

#define TT 4096
#define BB 64
#define PP 512
#define LN2F 0.69314718055994531f

__device__ __forceinline__ unsigned bf16_rne(float f) {
    unsigned u = __float_as_uint(f);
    return (u + 0x7FFFu + ((u >> 16) & 1u)) >> 16;
}

// prepass: x[t][b][5] -> xq[b*TT+t] = {bf16e0|bf16e1, bf16e2|bf16e3, f32 e4, 0}
__global__ __launch_bounds__(256, 1)
void ctc_prepass(const float* __restrict__ x, uint4* __restrict__ xq) {
    int j = blockIdx.x * 256 + threadIdx.x;        // j = b*TT + t
    int b = j >> 12, t = j & 4095;
    const float* r = x + ((size_t)t * BB + b) * 5;
    float e0 = __expf(r[0]), e1 = __expf(r[1]);
    float e2 = __expf(r[2]), e3 = __expf(r[3]);
    float e4 = __expf(r[4]);
    uint4 o;
    o.x = bf16_rne(e0) | (bf16_rne(e1) << 16);
    o.y = bf16_rne(e2) | (bf16_rne(e3) << 16);
    o.z = __float_as_uint(e4);
    o.w = 0u;
    xq[j] = o;
}

__device__ __forceinline__ void gload_lds16(const void* g, void* l) {
    auto gp = (const __attribute__((address_space(1))) void*)(uintptr_t)g;
    auto lp = (__attribute__((address_space(3))) void*)(uintptr_t)l;
    __builtin_amdgcn_global_load_lds(gp, lp, 16, 0, 0);
}

__global__ __launch_bounds__(64, 1)
void ctc_scan(const uint4* __restrict__ xq, const int* __restrict__ seqs,
              const int* __restrict__ seqlens, float* __restrict__ out) {
    __shared__ __align__(16) uint4 ring[512];      // 8 KB: 8 chunks x 64 rows
    __shared__ float garr[PP + 1];

    const int b = blockIdx.x;
    const int l = threadIdx.x;                     // 0..63
    const bool lane0 = (l == 0);
    const bool is16 = (l == 16), is32 = (l == 32), is48 = (l == 48);

    // lane n <- lane n-1, pure VALU: DPP row_shr:1 + patches at 16/32/48.
    auto shl1_i = [&](int s) -> int {
        int d = __builtin_amdgcn_update_dpp(s, s, 0x111, 0xF, 0xF, false);
        int s15 = __builtin_amdgcn_readlane(s, 15);
        int s31 = __builtin_amdgcn_readlane(s, 31);
        int s47 = __builtin_amdgcn_readlane(s, 47);
        d = is16 ? s15 : d;
        d = is32 ? s31 : d;
        d = is48 ? s47 : d;
        return d;
    };
    auto shl1_f = [&](float s) -> float {
        return __int_as_float(shl1_i(__float_as_int(s)));
    };

    // per-lane v_perm byte controls: pool = {w23 : w01}; index k -> bytes 2k,2k+1
    unsigned ctrl[4];
#pragma unroll
    for (int k = 0; k < 4; ++k) {
        unsigned i0 = (unsigned)seqs[b * PP + 8 * l + 2 * k];
        unsigned i1 = (unsigned)seqs[b * PP + 8 * l + 2 * k + 1];
        ctrl[k] = (2 * i0) | ((2 * i0 + 1) << 8) | ((2 * i1) << 16) | ((2 * i1 + 1) << 24);
    }

    const uint4* gsrc = xq + (size_t)b * TT;

    // ---- stage chunks 0..3 (1 call each: 64 lanes x 16 B = 64 rows) ----
#pragma unroll
    for (int c0 = 0; c0 < 4; ++c0)
        gload_lds16(gsrc + c0 * 64 + l, &ring[c0 * 64 + l]);
    asm volatile("s_waitcnt vmcnt(3)" ::: "memory");   // chunk 0 resident

    float F[8];
#pragma unroll
    for (int i = 0; i < 8; ++i) F[i] = 0.0f;
    float F0 = lane0 ? 1.0f : 0.0f;
    int M = 0, M0 = 0;

    uint4 rbuf0 = ring[0], rbuf1 = ring[1];        // rows 0,1
    int rowidx = 2;

    for (int c = 0; c < 64; ++c) {
        int cs = (c + 4 > 63) ? 63 : (c + 4);
        gload_lds16(gsrc + cs * 64 + l, &ring[((c + 4) & 7) * 64 + l]);
        asm volatile("s_waitcnt vmcnt(3)" ::: "memory");   // chunk c+1 resident

        for (int w8 = 0; w8 < 8; ++w8) {
            // ---- window bookkeeping (R7-validated) ----
            float m = F[0];
#pragma unroll
            for (int i = 1; i < 8; ++i) m = fmaxf(m, F[i]);
            int e2 = ((__float_as_int(m) >> 23) & 0xFF) - 127;
            e2 = (m > 0.0f) ? e2 : 0;
#pragma unroll
            for (int i = 0; i < 8; ++i) F[i] = ldexpf(F[i], -e2);
            M += e2;
            int e0 = ((__float_as_int(F0) >> 23) & 0xFF) - 127;
            e0 = (F0 > 0.0f) ? e0 : 0;
            F0 = ldexpf(F0, -e0);
            M0 += e0;

            const int Ml = shl1_i(M);
            int dl = lane0 ? (M0 - M) : (Ml - M);
            int dlc = dl > 0 ? dl : 0;             // down-only self-squash
#pragma unroll
            for (int i = 0; i < 8; ++i) F[i] = ldexpf(F[i], -dlc);
            M += dlc;
            int dn = Ml - M; dn = dn > 0 ? 0 : dn;
            int d0 = M0 - M; d0 = d0 > 0 ? 0 : d0;
            const float sA  = ldexpf(1.0f, dn);
            const float sF0 = ldexpf(1.0f, d0);

            // ---- 8 steps ----
#pragma unroll
            for (int u = 0; u < 8; ++u) {
                const uint4 row = (u & 1) ? rbuf1 : rbuf0;
                // prefetch row (rowidx) into the slot just freed (2 ahead)
                if (u & 1) rbuf1 = ring[rowidx & 511];
                else       rbuf0 = ring[rowidx & 511];
                ++rowidx;

                const float S = __uint_as_float(row.z);
                unsigned p0 = __builtin_amdgcn_perm(row.y, row.x, ctrl[0]);
                unsigned p1 = __builtin_amdgcn_perm(row.y, row.x, ctrl[1]);
                unsigned p2 = __builtin_amdgcn_perm(row.y, row.x, ctrl[2]);
                unsigned p3 = __builtin_amdgcn_perm(row.y, row.x, ctrl[3]);
                const float V0 = __uint_as_float(p0 << 16);
                const float V1 = __uint_as_float(p0 & 0xFFFF0000u);
                const float V2 = __uint_as_float(p1 << 16);
                const float V3 = __uint_as_float(p1 & 0xFFFF0000u);
                const float V4 = __uint_as_float(p2 << 16);
                const float V5 = __uint_as_float(p2 & 0xFFFF0000u);
                const float V6 = __uint_as_float(p3 << 16);
                const float V7 = __uint_as_float(p3 & 0xFFFF0000u);

                const float Fl = shl1_f(F[7]);     // pre-update boundary (VALU only)
                const float fin = lane0 ? F0 * sF0 : Fl * sA;

                F[7] = fmaf(F[7], S, F[6] * V7);
                F[6] = fmaf(F[6], S, F[5] * V6);
                F[5] = fmaf(F[5], S, F[4] * V5);
                F[4] = fmaf(F[4], S, F[3] * V4);
                F[3] = fmaf(F[3], S, F[2] * V3);
                F[2] = fmaf(F[2], S, F[1] * V2);
                F[1] = fmaf(F[1], S, F[0] * V1);
                F[0] = fmaf(F[0], S, fin * V0);
                F0 *= S;
            }
        }
    }

    // ---- epilogue: log2 reconstruction (denormal-safe) ----
#pragma unroll
    for (int i = 0; i < 8; ++i) {
        float v = fmaxf(F[i] * 16777216.0f, 1e-38f);
        garr[8 * l + 1 + i] = __log2f(v) - 24.0f + (float)M;
    }
    if (lane0) {
        float v0 = fmaxf(F0 * 16777216.0f, 1e-38f);
        garr[0] = __log2f(v0) - 24.0f + (float)M0;
    }
    __syncthreads();
    if (lane0) {
        const int sl = seqlens[b];
        out[b] = -(garr[sl] * LN2F) / (float)TT;
    }
}

extern "C" void kernel_launch(void* const* d_in, const int* in_sizes, int n_in,
                              void* d_out, int out_size, void* d_ws, size_t ws_size,
                              hipStream_t stream) {
    const float* x       = (const float*)d_in[0];
    const int*   seqs    = (const int*)d_in[1];
    const int*   seqlens = (const int*)d_in[2];
    float*       out     = (float*)d_out;
    uint4*       xq      = (uint4*)d_ws;           // TT*BB rows x 16 B = 4 MB

    ctc_prepass<<<(TT * BB) / 256, 256, 0, stream>>>(x, xq);
    ctc_scan<<<BB, 64, 0, stream>>>(xq, seqs, seqlens, out);
}

// Round 10
// 380.999 us; speedup vs baseline: 1.3371x; 1.1936x over previous
//
#include <hip/hip_runtime.h>

// CTC-like forward scan. R10 = R9 structure with three issue-side fixes:
// (1) boundary via ONE v_mov_dpp wave_shr:1 (crosses 16-lane rows on CDNA;
//     lane0 keeps old -> overridden by cndmask with F0) instead of the 7-op
//     DPP+readlane+cndmask sequence (removes VALU->SALU hazard nops too);
// (2) w8 window loop kept ROLLED (#pragma unroll 1): inner code ~3.5 KB,
//     I$-resident (R7-R9 all plateaued ~230-260 cy/step — I-fetch suspect);
// (3) fin select folded: per-window sAx = lane0 ? sF0 : sA, per-step 1 cndmask.
// Everything else verbatim from R9 (passed, absmax 9.8e-4): packed bf16 rows,
// one ds_read_b128/step prefetched 2 ahead, global_load_lds staging 4 chunks
// ahead, per-lane exponent frames with down-only alignment, renorm every 8.

#define TT 4096
#define BB 64
#define PP 512
#define LN2F 0.69314718055994531f

__device__ __forceinline__ unsigned bf16_rne(float f) {
    unsigned u = __float_as_uint(f);
    return (u + 0x7FFFu + ((u >> 16) & 1u)) >> 16;
}

// prepass: x[t][b][5] -> xq[b*TT+t] = {bf16e0|bf16e1, bf16e2|bf16e3, f32 e4, 0}
__global__ __launch_bounds__(256, 1)
void ctc_prepass(const float* __restrict__ x, uint4* __restrict__ xq) {
    int j = blockIdx.x * 256 + threadIdx.x;        // j = b*TT + t
    int b = j >> 12, t = j & 4095;
    const float* r = x + ((size_t)t * BB + b) * 5;
    float e0 = __expf(r[0]), e1 = __expf(r[1]);
    float e2 = __expf(r[2]), e3 = __expf(r[3]);
    float e4 = __expf(r[4]);
    uint4 o;
    o.x = bf16_rne(e0) | (bf16_rne(e1) << 16);
    o.y = bf16_rne(e2) | (bf16_rne(e3) << 16);
    o.z = __float_as_uint(e4);
    o.w = 0u;
    xq[j] = o;
}

__device__ __forceinline__ void gload_lds16(const void* g, void* l) {
    auto gp = (const __attribute__((address_space(1))) void*)(uintptr_t)g;
    auto lp = (__attribute__((address_space(3))) void*)(uintptr_t)l;
    __builtin_amdgcn_global_load_lds(gp, lp, 16, 0, 0);
}

// lane n <- lane n-1 across the whole wave; lane 0 keeps old (we override it).
__device__ __forceinline__ int shl1w_i(int s) {
    return __builtin_amdgcn_update_dpp(s, s, 0x138 /*wave_shr:1*/, 0xF, 0xF, false);
}
__device__ __forceinline__ float shl1w_f(float s) {
    return __int_as_float(shl1w_i(__float_as_int(s)));
}

__global__ __launch_bounds__(64, 1)
void ctc_scan(const uint4* __restrict__ xq, const int* __restrict__ seqs,
              const int* __restrict__ seqlens, float* __restrict__ out) {
    __shared__ __align__(16) uint4 ring[512];      // 8 KB: 8 chunks x 64 rows
    __shared__ float garr[PP + 1];

    const int b = blockIdx.x;
    const int l = threadIdx.x;                     // 0..63
    const bool lane0 = (l == 0);

    // per-lane v_perm byte controls: pool = {w23 : w01}; index k -> bytes 2k,2k+1
    unsigned ctrl[4];
#pragma unroll
    for (int k = 0; k < 4; ++k) {
        unsigned i0 = (unsigned)seqs[b * PP + 8 * l + 2 * k];
        unsigned i1 = (unsigned)seqs[b * PP + 8 * l + 2 * k + 1];
        ctrl[k] = (2 * i0) | ((2 * i0 + 1) << 8) | ((2 * i1) << 16) | ((2 * i1 + 1) << 24);
    }

    const uint4* gsrc = xq + (size_t)b * TT;

    // ---- stage chunks 0..3 (1 call each: 64 lanes x 16 B = 64 rows) ----
#pragma unroll
    for (int c0 = 0; c0 < 4; ++c0)
        gload_lds16(gsrc + c0 * 64 + l, &ring[c0 * 64 + l]);
    asm volatile("s_waitcnt vmcnt(3)" ::: "memory");   // chunk 0 resident

    float F[8];
#pragma unroll
    for (int i = 0; i < 8; ++i) F[i] = 0.0f;
    float F0 = lane0 ? 1.0f : 0.0f;
    int M = 0, M0 = 0;

    uint4 rbuf0 = ring[0], rbuf1 = ring[1];        // rows 0,1
    int rowidx = 2;

#pragma unroll 1
    for (int c = 0; c < 64; ++c) {
        int cs = (c + 4 > 63) ? 63 : (c + 4);
        gload_lds16(gsrc + cs * 64 + l, &ring[((c + 4) & 7) * 64 + l]);
        asm volatile("s_waitcnt vmcnt(3)" ::: "memory");   // chunk c+1 resident

#pragma unroll 1
        for (int w8 = 0; w8 < 8; ++w8) {
            // ---- window bookkeeping (R7/R9-validated) ----
            float m = F[0];
#pragma unroll
            for (int i = 1; i < 8; ++i) m = fmaxf(m, F[i]);
            int e2 = ((__float_as_int(m) >> 23) & 0xFF) - 127;
            e2 = (m > 0.0f) ? e2 : 0;
#pragma unroll
            for (int i = 0; i < 8; ++i) F[i] = ldexpf(F[i], -e2);
            M += e2;
            int e0 = ((__float_as_int(F0) >> 23) & 0xFF) - 127;
            e0 = (F0 > 0.0f) ? e0 : 0;
            F0 = ldexpf(F0, -e0);
            M0 += e0;

            const int Ml = shl1w_i(M);
            int dl = lane0 ? (M0 - M) : (Ml - M);
            int dlc = dl > 0 ? dl : 0;             // down-only self-squash
#pragma unroll
            for (int i = 0; i < 8; ++i) F[i] = ldexpf(F[i], -dlc);
            M += dlc;
            int dn = Ml - M; dn = dn > 0 ? 0 : dn;
            int d0 = M0 - M; d0 = d0 > 0 ? 0 : d0;
            const float sA  = ldexpf(1.0f, dn);
            const float sF0 = ldexpf(1.0f, d0);
            const float sAx = lane0 ? sF0 : sA;    // folded per-window select

            // ---- 8 steps ----
#pragma unroll
            for (int u = 0; u < 8; ++u) {
                const uint4 row = (u & 1) ? rbuf1 : rbuf0;
                // prefetch row (rowidx) into the slot just freed (2 ahead)
                if (u & 1) rbuf1 = ring[rowidx & 511];
                else       rbuf0 = ring[rowidx & 511];
                ++rowidx;

                const float S = __uint_as_float(row.z);
                unsigned p0 = __builtin_amdgcn_perm(row.y, row.x, ctrl[0]);
                unsigned p1 = __builtin_amdgcn_perm(row.y, row.x, ctrl[1]);
                unsigned p2 = __builtin_amdgcn_perm(row.y, row.x, ctrl[2]);
                unsigned p3 = __builtin_amdgcn_perm(row.y, row.x, ctrl[3]);
                const float V0 = __uint_as_float(p0 << 16);
                const float V1 = __uint_as_float(p0 & 0xFFFF0000u);
                const float V2 = __uint_as_float(p1 << 16);
                const float V3 = __uint_as_float(p1 & 0xFFFF0000u);
                const float V4 = __uint_as_float(p2 << 16);
                const float V5 = __uint_as_float(p2 & 0xFFFF0000u);
                const float V6 = __uint_as_float(p3 << 16);
                const float V7 = __uint_as_float(p3 & 0xFFFF0000u);

                const float Flr = shl1w_f(F[7]);   // 1 DPP: lane n <- n-1
                const float fin = (lane0 ? F0 : Flr) * sAx;

                F[7] = fmaf(F[7], S, F[6] * V7);
                F[6] = fmaf(F[6], S, F[5] * V6);
                F[5] = fmaf(F[5], S, F[4] * V5);
                F[4] = fmaf(F[4], S, F[3] * V4);
                F[3] = fmaf(F[3], S, F[2] * V3);
                F[2] = fmaf(F[2], S, F[1] * V2);
                F[1] = fmaf(F[1], S, F[0] * V1);
                F[0] = fmaf(F[0], S, fin * V0);
                F0 *= S;
            }
        }
    }

    // ---- epilogue: log2 reconstruction (denormal-safe) ----
#pragma unroll
    for (int i = 0; i < 8; ++i) {
        float v = fmaxf(F[i] * 16777216.0f, 1e-38f);
        garr[8 * l + 1 + i] = __log2f(v) - 24.0f + (float)M;
    }
    if (lane0) {
        float v0 = fmaxf(F0 * 16777216.0f, 1e-38f);
        garr[0] = __log2f(v0) - 24.0f + (float)M0;
    }
    __syncthreads();
    if (lane0) {
        const int sl = seqlens[b];
        out[b] = -(garr[sl] * LN2F) / (float)TT;
    }
}

extern "C" void kernel_launch(void* const* d_in, const int* in_sizes, int n_in,
                              void* d_out, int out_size, void* d_ws, size_t ws_size,
                              hipStream_t stream) {
    const float* x       = (const float*)d_in[0];
    const int*   seqs    = (const int*)d_in[1];
    const int*   seqlens = (const int*)d_in[2];
    float*       out     = (float*)d_out;
    uint4*       xq      = (uint4*)d_ws;           // TT*BB rows x 16 B = 4 MB

    ctc_prepass<<<(TT * BB) / 256, 256, 0, stream>>>(x, xq);
    ctc_scan<<<BB, 64, 0, stream>>>(xq, seqs, seqlens, out);
}

// Round 11
// 356.112 us; speedup vs baseline: 1.4306x; 1.0699x over previous
//
#include <hip/hip_runtime.h>

// CTC-like forward scan. R11 = R10 with scheduler-proof LDS prefetching:
// - 8-row register windows (wA/wB), burst of 8 ds_read_b128 issued at window
//   start for the NEXT window, pinned by an empty asm memory clobber so the
//   compiler cannot sink the loads to their use sites (R10's ~120cy/step
//   stall = ds_read latency exposed by collapsed 2-deep double-buffer).
// - Fused renorm+squash: one 8-ldexp pass per window (exchange post-renorm
//   frame Mp first, apply total shift once).
// - xq layout flipped to [t*64+b]: prepass fully coalesced on both sides;
//   scan staging is a 1KB-stride gather via global_load_lds (4 chunks ahead,
//   latency-tolerant, L2-resident).
// Numerics identical to R9/R10 (passed, absmax 9.77e-4): packed bf16 V rows,
// f32 S, per-lane exponent frames, down-only alignment, renorm every 8 steps,
// boundary via one v_mov_dpp wave_shr:1.

#define TT 4096
#define BB 64
#define PP 512
#define LN2F 0.69314718055994531f

__device__ __forceinline__ unsigned bf16_rne(float f) {
    unsigned u = __float_as_uint(f);
    return (u + 0x7FFFu + ((u >> 16) & 1u)) >> 16;
}

// prepass: x[t][b][5] -> xq[t*64+b] = {bf16e0|bf16e1, bf16e2|bf16e3, f32 e4, 0}
// consecutive threads = consecutive b: reads 20B/lane contiguous, writes 16B/lane
// contiguous -> fully coalesced both sides.
__global__ __launch_bounds__(256, 1)
void ctc_prepass(const float* __restrict__ x, uint4* __restrict__ xq) {
    int j = blockIdx.x * 256 + threadIdx.x;        // j = t*64 + b
    const float* r = x + (size_t)j * 5;
    float e0 = __expf(r[0]), e1 = __expf(r[1]);
    float e2 = __expf(r[2]), e3 = __expf(r[3]);
    float e4 = __expf(r[4]);
    uint4 o;
    o.x = bf16_rne(e0) | (bf16_rne(e1) << 16);
    o.y = bf16_rne(e2) | (bf16_rne(e3) << 16);
    o.z = __float_as_uint(e4);
    o.w = 0u;
    xq[j] = o;
}

__device__ __forceinline__ void gload_lds16(const void* g, void* l) {
    auto gp = (const __attribute__((address_space(1))) void*)(uintptr_t)g;
    auto lp = (__attribute__((address_space(3))) void*)(uintptr_t)l;
    __builtin_amdgcn_global_load_lds(gp, lp, 16, 0, 0);
}

// lane n <- lane n-1 across the whole wave; lane 0 keeps old (overridden).
__device__ __forceinline__ int shl1w_i(int s) {
    return __builtin_amdgcn_update_dpp(s, s, 0x138 /*wave_shr:1*/, 0xF, 0xF, false);
}
__device__ __forceinline__ float shl1w_f(float s) {
    return __int_as_float(shl1w_i(__float_as_int(s)));
}

__global__ __launch_bounds__(64, 1)
void ctc_scan(const uint4* __restrict__ xq, const int* __restrict__ seqs,
              const int* __restrict__ seqlens, float* __restrict__ out) {
    __shared__ __align__(16) uint4 ring[512];      // 8 KB: 8 chunks x 64 rows
    __shared__ float garr[PP + 1];

    const int b = blockIdx.x;
    const int l = threadIdx.x;                     // 0..63
    const bool lane0 = (l == 0);

    // per-lane v_perm byte controls (validated R9/R10 convention)
    unsigned ctrl[4];
#pragma unroll
    for (int k = 0; k < 4; ++k) {
        unsigned i0 = (unsigned)seqs[b * PP + 8 * l + 2 * k];
        unsigned i1 = (unsigned)seqs[b * PP + 8 * l + 2 * k + 1];
        ctrl[k] = (2 * i0) | ((2 * i0 + 1) << 8) | ((2 * i1) << 16) | ((2 * i1 + 1) << 24);
    }

    // xq row (t,b) at xq[t*64+b]; chunk c, lane l stages row t=c*64+l.
    const uint4* gsrc = xq + b;                    // + 64*t

    // ---- stage chunks 0..3 ----
#pragma unroll
    for (int c0 = 0; c0 < 4; ++c0)
        gload_lds16(gsrc + (size_t)(c0 * 64 + l) * 64, &ring[c0 * 64 + l]);
    asm volatile("s_waitcnt vmcnt(3)" ::: "memory");   // chunk 0 resident

    float F[8];
#pragma unroll
    for (int i = 0; i < 8; ++i) F[i] = 0.0f;
    float F0 = lane0 ? 1.0f : 0.0f;
    int M = 0, M0 = 0;

    uint4 wA[8], wB[8];
#pragma unroll
    for (int i = 0; i < 8; ++i) wA[i] = ring[i];   // window 0
    int nrow = 8;                                  // ring row of next window

    auto window = [&](uint4 (&cur)[8], uint4 (&nxt)[8]) {
        // ---- burst-load next window, pin above consumption ----
        const int rb = nrow & 511;
        nrow += 8;
#pragma unroll
        for (int i = 0; i < 8; ++i) nxt[i] = ring[rb + i];
        asm volatile("" ::: "memory");

        // ---- fused window bookkeeping ----
        float m = F[0];
#pragma unroll
        for (int i = 1; i < 8; ++i) m = fmaxf(m, F[i]);
        int e2 = ((__float_as_int(m) >> 23) & 0xFF) - 127;
        e2 = (m > 0.0f) ? e2 : 0;
        const int Mp = M + e2;                     // post-renorm frame
        const int Mlp = shl1w_i(Mp);               // neighbor's post-renorm frame
        int e0 = ((__float_as_int(F0) >> 23) & 0xFF) - 127;
        e0 = (F0 > 0.0f) ? e0 : 0;
        F0 = ldexpf(F0, -e0);
        M0 += e0;
        int dl = lane0 ? (M0 - Mp) : (Mlp - Mp);
        int dlc = dl > 0 ? dl : 0;                 // down-only self-squash
        const int Mnew = Mp + dlc;
        const int sh = Mnew - M;                   // = e2 + dlc >= 0
#pragma unroll
        for (int i = 0; i < 8; ++i) F[i] = ldexpf(F[i], -sh);
        M = Mnew;
        int dn = Mlp - M; dn = dn > 0 ? 0 : dn;
        int d0 = M0 - M;  d0 = d0 > 0 ? 0 : d0;
        const float sA  = ldexpf(1.0f, dn);
        const float sF0 = ldexpf(1.0f, d0);
        const float sAx = lane0 ? sF0 : sA;

        // ---- 8 steps ----
#pragma unroll
        for (int u = 0; u < 8; ++u) {
            const uint4 row = cur[u];
            const float S = __uint_as_float(row.z);
            unsigned p0 = __builtin_amdgcn_perm(row.y, row.x, ctrl[0]);
            unsigned p1 = __builtin_amdgcn_perm(row.y, row.x, ctrl[1]);
            unsigned p2 = __builtin_amdgcn_perm(row.y, row.x, ctrl[2]);
            unsigned p3 = __builtin_amdgcn_perm(row.y, row.x, ctrl[3]);
            const float V0 = __uint_as_float(p0 << 16);
            const float V1 = __uint_as_float(p0 & 0xFFFF0000u);
            const float V2 = __uint_as_float(p1 << 16);
            const float V3 = __uint_as_float(p1 & 0xFFFF0000u);
            const float V4 = __uint_as_float(p2 << 16);
            const float V5 = __uint_as_float(p2 & 0xFFFF0000u);
            const float V6 = __uint_as_float(p3 << 16);
            const float V7 = __uint_as_float(p3 & 0xFFFF0000u);

            const float Flr = shl1w_f(F[7]);       // 1 DPP: lane n <- n-1
            const float fin = (lane0 ? F0 : Flr) * sAx;

            F[7] = fmaf(F[7], S, F[6] * V7);
            F[6] = fmaf(F[6], S, F[5] * V6);
            F[5] = fmaf(F[5], S, F[4] * V5);
            F[4] = fmaf(F[4], S, F[3] * V4);
            F[3] = fmaf(F[3], S, F[2] * V3);
            F[2] = fmaf(F[2], S, F[1] * V2);
            F[1] = fmaf(F[1], S, F[0] * V1);
            F[0] = fmaf(F[0], S, fin * V0);
            F0 *= S;
        }
    };

#pragma unroll 1
    for (int c = 0; c < 64; ++c) {
        int cs = (c + 4 > 63) ? 63 : (c + 4);
        gload_lds16(gsrc + (size_t)(cs * 64 + l) * 64, &ring[((c + 4) & 7) * 64 + l]);
        asm volatile("s_waitcnt vmcnt(3)" ::: "memory");   // chunk c+1 resident

#pragma unroll 1
        for (int pr = 0; pr < 4; ++pr) {
            window(wA, wB);
            window(wB, wA);
        }
    }

    // ---- epilogue: log2 reconstruction (denormal-safe) ----
#pragma unroll
    for (int i = 0; i < 8; ++i) {
        float v = fmaxf(F[i] * 16777216.0f, 1e-38f);
        garr[8 * l + 1 + i] = __log2f(v) - 24.0f + (float)M;
    }
    if (lane0) {
        float v0 = fmaxf(F0 * 16777216.0f, 1e-38f);
        garr[0] = __log2f(v0) - 24.0f + (float)M0;
    }
    __syncthreads();
    if (lane0) {
        const int sl = seqlens[b];
        out[b] = -(garr[sl] * LN2F) / (float)TT;
    }
}

extern "C" void kernel_launch(void* const* d_in, const int* in_sizes, int n_in,
                              void* d_out, int out_size, void* d_ws, size_t ws_size,
                              hipStream_t stream) {
    const float* x       = (const float*)d_in[0];
    const int*   seqs    = (const int*)d_in[1];
    const int*   seqlens = (const int*)d_in[2];
    float*       out     = (float*)d_out;
    uint4*       xq      = (uint4*)d_ws;           // TT*BB rows x 16 B = 4 MB

    ctc_prepass<<<(TT * BB) / 256, 256, 0, stream>>>(x, xq);
    ctc_scan<<<BB, 64, 0, stream>>>(xq, seqs, seqlens, out);
}